// Round 1
// baseline (645.750 us; speedup 1.0000x reference)
//
#include <hip/hip_runtime.h>
#include <hip/hip_bf16.h>

// Grouped GEMM: out[e] = x[e] @ W[e]^T
//   x: [8, 4096, 128] fp32, W: [8, 4096, 128] fp32 -> out: [8, 4096, 4096] fp32
// Write-bound (537 MB out vs 34.4 GFLOP). In-kernel fp32->bf16 RNE cast +
// 16x16x32 bf16 MFMA (fp32 accum). K=128 entirely in LDS -> no global K-loop.
//
// R2 -> R3:
//  (a) MFMA operand swap: acc = mfma(bv, av) instead of mfma(av, bv). Operand
//      register layouts are symmetric (lane holds row=l16, k=quad*8..), so the
//      swap computes identical dot products with the C-layout transposed:
//      each lane's 4 acc regs = 4 CONSECUTIVE OUT-columns of one row ->
//      epilogue is 8 global_store_dwordx4 per thread instead of 32 scalar
//      stores (4x fewer store insts, all full 64B sectors).
//  (b) XCD-aware swizzle: 8192 wgs round-robin across 8 XCDs (wg%8 = XCD id);
//      remap so XCD i owns expert i exactly (1024 wgs). Per-XCD L2 (4 MiB)
//      then holds exactly x[e] (2 MB) + W[e] (2 MB); x tiles are fetched once
//      per chip instead of once per XCD.
//  (c) Stores stay nontemporal: output is never re-read, and nt keeps the
//      streaming 537 MB from evicting the L2-resident x/W read set.

#define NEXP 8
#define NROW 4096
#define KD   128
#define NOUT 4096
#define TILE 128

typedef __attribute__((ext_vector_type(8))) short bf16x8;
typedef __attribute__((ext_vector_type(4))) float f32x4;

// Pack two fp32 into two bf16 (round-to-nearest-even) in one uint.
__device__ __forceinline__ unsigned int pack2_bf16(float lo, float hi) {
  unsigned int ulo = __float_as_uint(lo);
  ulo += 0x7fffu + ((ulo >> 16) & 1u);
  unsigned int uhi = __float_as_uint(hi);
  uhi += 0x7fffu + ((uhi >> 16) & 1u);
  return (ulo >> 16) | (uhi & 0xffff0000u);
}

__global__ __launch_bounds__(512, 4)
void moe_gemm_bf16(const float* __restrict__ X, const float* __restrict__ W,
                   float* __restrict__ Out) {
  // Row-major [row][k] bf16 tiles, 16B-chunk XOR swizzle (cs = c ^ (row&15)).
  __shared__ unsigned short As[TILE * KD];
  __shared__ unsigned short Bs[TILE * KD];

  // XCD swizzle: wg%8 = XCD id (round-robin dispatch), 1024 wgs per XCD =
  // exactly one expert's 32x32 tile grid. Within an expert, col-tile fastest
  // (consecutive wgs on an XCD sweep cols of one row-panel -> x-tile reuse).
  const int wg   = blockIdx.x;
  const int e    = wg & 7;
  const int rem  = wg >> 3;              // 0..1023 within expert
  const int row0 = (rem >> 5) * TILE;
  const int col0 = (rem & 31) * TILE;
  const int t    = threadIdx.x;

  const float* xg = X + ((size_t)e * NROW + row0) * KD;
  const float* wg_ = W + ((size_t)e * NOUT + col0) * KD;

  // Stage 16384 floats per matrix: 512 thr x 4 rounds x 8 floats.
#pragma unroll
  for (int r = 0; r < 4; ++r) {
    const int flat = r * 4096 + t * 8;     // 8-float chunk, never crosses a row
    const int row  = flat >> 7;
    const int c    = (flat >> 3) & 15;     // 16B chunk within row
    const int cs   = c ^ (row & 15);
    const int lidx = row * KD + cs * 8;    // ushort index

    float4 a0 = *(const float4*)(xg + flat);
    float4 a1 = *(const float4*)(xg + flat + 4);
    float4 b0 = *(const float4*)(wg_ + flat);
    float4 b1 = *(const float4*)(wg_ + flat + 4);

    uint4 ap, bp;
    ap.x = pack2_bf16(a0.x, a0.y); ap.y = pack2_bf16(a0.z, a0.w);
    ap.z = pack2_bf16(a1.x, a1.y); ap.w = pack2_bf16(a1.z, a1.w);
    bp.x = pack2_bf16(b0.x, b0.y); bp.y = pack2_bf16(b0.z, b0.w);
    bp.z = pack2_bf16(b1.x, b1.y); bp.w = pack2_bf16(b1.z, b1.w);

    *(uint4*)(&As[lidx]) = ap;
    *(uint4*)(&Bs[lidx]) = bp;
  }
  __syncthreads();

  const int lane = t & 63;
  const int wave = t >> 6;          // 0..7
  const int quad = lane >> 4;
  const int l16  = lane & 15;
  const int wm   = (wave & 1) * 64;   // wave's row offset in tile (2 in M)
  const int wn   = (wave >> 1) * 32;  // wave's col offset in tile (4 in N)

  f32x4 acc[4][2];
#pragma unroll
  for (int i = 0; i < 4; ++i)
#pragma unroll
    for (int j = 0; j < 2; ++j)
      acc[i][j] = (f32x4)(0.0f);

  // K = 128 = 4 steps of 32. Frag: lane holds [row=l16][k = quad*8 + 0..7].
#pragma unroll
  for (int ks = 0; ks < 4; ++ks) {
    const int c  = ks * 4 + quad;       // 16B chunk index along k
    const int cs = c ^ l16;             // (row & 15) == l16 for all frag rows
    bf16x8 av[4], bv[2];
#pragma unroll
    for (int i = 0; i < 4; ++i) {
      const int row = wm + i * 16 + l16;
      av[i] = *(const bf16x8*)(&As[row * KD + cs * 8]);
    }
#pragma unroll
    for (int j = 0; j < 2; ++j) {
      const int row = wn + j * 16 + l16;
      bv[j] = *(const bf16x8*)(&Bs[row * KD + cs * 8]);
    }
    // SWAPPED operands: D[m][n] = sum_k W[wn+j*16+m][k] * x[wm+i*16+n][k],
    // C-layout (verified map): n = l16 (x row), m = quad*4 + v (OUT col).
#pragma unroll
    for (int i = 0; i < 4; ++i)
#pragma unroll
      for (int j = 0; j < 2; ++j)
        acc[i][j] = __builtin_amdgcn_mfma_f32_16x16x32_bf16(bv[j], av[i],
                                                            acc[i][j], 0, 0, 0);
  }

  // Epilogue: lane (quad,l16) holds, per (i,j), out[row0+wm+i*16+l16]
  // [col0+wn+j*16+quad*4 + 0..3] -> one dwordx4 nt store per fragment.
  float* og = Out + ((size_t)e * NROW + row0 + wm + l16) * NOUT
                  + col0 + wn + quad * 4;
#pragma unroll
  for (int i = 0; i < 4; ++i) {
    float* orow = og + (size_t)(i * 16) * NOUT;
#pragma unroll
    for (int j = 0; j < 2; ++j)
      __builtin_nontemporal_store(acc[i][j], (f32x4*)(orow + j * 16));
  }
}

extern "C" void kernel_launch(void* const* d_in, const int* in_sizes, int n_in,
                              void* d_out, int out_size, void* d_ws, size_t ws_size,
                              hipStream_t stream) {
  const float* X = (const float*)d_in[0];
  const float* W = (const float*)d_in[1];
  float* Out = (float*)d_out;
  dim3 grid(NEXP * (NROW / TILE) * (NOUT / TILE), 1, 1);  // 8192
  moe_gemm_bf16<<<grid, dim3(512, 1, 1), 0, stream>>>(X, W, Out);
}

// Round 2
// 635.073 us; speedup vs baseline: 1.0168x; 1.0168x over previous
//
#include <hip/hip_runtime.h>
#include <hip/hip_bf16.h>

// Grouped GEMM: out[e] = x[e] @ W[e]^T
//   x: [8, 4096, 128] fp32, W: [8, 4096, 128] fp32 -> out: [8, 4096, 4096] fp32
// Write-bound (537 MB out vs 34.4 GFLOP). In-kernel fp32->bf16 RNE cast +
// 16x16x32 bf16 MFMA (fp32 accum). K=128 entirely in LDS -> no global K-loop.
//
// R3 -> R4 (post-mortem of R3's +50us regression):
//  REVERTED: 1D grid + expert=wg&7 XCD mapping. It assumed wg%8 -> XCD
//    round-robin; if the real assignment differs, each XCD's concurrent set
//    spans multiple experts -> x row-panels thrash L2 -> extra HBM fetch.
//    Back to the dispatch-order-robust 3D grid (32,32,8): expert varies
//    slowest, so all concurrent wgs share 1-2 experts (4 MB working set fits
//    any XCD's L2 no matter how wgs are assigned).
//  KEPT: MFMA operand swap (acc = mfma(bv, av)). Operand layouts are
//    symmetric (lane holds row=l16, k=quad*8..), so swapping transposes the
//    C-layout: each lane's 4 acc regs = 4 consecutive OUT-columns of one row
//    -> 8 global_store_dwordx4 per thread instead of 32 scalar stores.

#define NEXP 8
#define NROW 4096
#define KD   128
#define NOUT 4096
#define TILE 128

typedef __attribute__((ext_vector_type(8))) short bf16x8;
typedef __attribute__((ext_vector_type(4))) float f32x4;

// Pack two fp32 into two bf16 (round-to-nearest-even) in one uint.
__device__ __forceinline__ unsigned int pack2_bf16(float lo, float hi) {
  unsigned int ulo = __float_as_uint(lo);
  ulo += 0x7fffu + ((ulo >> 16) & 1u);
  unsigned int uhi = __float_as_uint(hi);
  uhi += 0x7fffu + ((uhi >> 16) & 1u);
  return (ulo >> 16) | (uhi & 0xffff0000u);
}

__global__ __launch_bounds__(512, 4)
void moe_gemm_bf16(const float* __restrict__ X, const float* __restrict__ W,
                   float* __restrict__ Out) {
  // Row-major [row][k] bf16 tiles, 16B-chunk XOR swizzle (cs = c ^ (row&15)).
  __shared__ unsigned short As[TILE * KD];
  __shared__ unsigned short Bs[TILE * KD];

  const int e    = blockIdx.z;
  const int row0 = blockIdx.y * TILE;
  const int col0 = blockIdx.x * TILE;
  const int t    = threadIdx.x;

  const float* xg = X + ((size_t)e * NROW + row0) * KD;
  const float* wg = W + ((size_t)e * NOUT + col0) * KD;

  // Stage 16384 floats per matrix: 512 thr x 4 rounds x 8 floats.
#pragma unroll
  for (int r = 0; r < 4; ++r) {
    const int flat = r * 4096 + t * 8;     // 8-float chunk, never crosses a row
    const int row  = flat >> 7;
    const int c    = (flat >> 3) & 15;     // 16B chunk within row
    const int cs   = c ^ (row & 15);
    const int lidx = row * KD + cs * 8;    // ushort index

    float4 a0 = *(const float4*)(xg + flat);
    float4 a1 = *(const float4*)(xg + flat + 4);
    float4 b0 = *(const float4*)(wg + flat);
    float4 b1 = *(const float4*)(wg + flat + 4);

    uint4 ap, bp;
    ap.x = pack2_bf16(a0.x, a0.y); ap.y = pack2_bf16(a0.z, a0.w);
    ap.z = pack2_bf16(a1.x, a1.y); ap.w = pack2_bf16(a1.z, a1.w);
    bp.x = pack2_bf16(b0.x, b0.y); bp.y = pack2_bf16(b0.z, b0.w);
    bp.z = pack2_bf16(b1.x, b1.y); bp.w = pack2_bf16(b1.z, b1.w);

    *(uint4*)(&As[lidx]) = ap;
    *(uint4*)(&Bs[lidx]) = bp;
  }
  __syncthreads();

  const int lane = t & 63;
  const int wave = t >> 6;          // 0..7
  const int quad = lane >> 4;
  const int l16  = lane & 15;
  const int wm   = (wave & 1) * 64;   // wave's row offset in tile (2 in M)
  const int wn   = (wave >> 1) * 32;  // wave's col offset in tile (4 in N)

  f32x4 acc[4][2];
#pragma unroll
  for (int i = 0; i < 4; ++i)
#pragma unroll
    for (int j = 0; j < 2; ++j)
      acc[i][j] = (f32x4)(0.0f);

  // K = 128 = 4 steps of 32. Frag: lane holds [row=l16][k = quad*8 + 0..7].
#pragma unroll
  for (int ks = 0; ks < 4; ++ks) {
    const int c  = ks * 4 + quad;       // 16B chunk index along k
    const int cs = c ^ l16;             // (row & 15) == l16 for all frag rows
    bf16x8 av[4], bv[2];
#pragma unroll
    for (int i = 0; i < 4; ++i) {
      const int row = wm + i * 16 + l16;
      av[i] = *(const bf16x8*)(&As[row * KD + cs * 8]);
    }
#pragma unroll
    for (int j = 0; j < 2; ++j) {
      const int row = wn + j * 16 + l16;
      bv[j] = *(const bf16x8*)(&Bs[row * KD + cs * 8]);
    }
    // SWAPPED operands: lane's 4 acc regs = 4 consecutive OUT-cols of one row.
#pragma unroll
    for (int i = 0; i < 4; ++i)
#pragma unroll
      for (int j = 0; j < 2; ++j)
        acc[i][j] = __builtin_amdgcn_mfma_f32_16x16x32_bf16(bv[j], av[i],
                                                            acc[i][j], 0, 0, 0);
  }

  // Epilogue: lane (quad,l16) holds, per (i,j), out[row0+wm+i*16+l16]
  // [col0+wn+j*16+quad*4 + 0..3] -> one dwordx4 nt store per fragment.
  float* og = Out + ((size_t)e * NROW + row0 + wm + l16) * NOUT
                  + col0 + wn + quad * 4;
#pragma unroll
  for (int i = 0; i < 4; ++i) {
    float* orow = og + (size_t)(i * 16) * NOUT;
#pragma unroll
    for (int j = 0; j < 2; ++j)
      __builtin_nontemporal_store(acc[i][j], (f32x4*)(orow + j * 16));
  }
}

extern "C" void kernel_launch(void* const* d_in, const int* in_sizes, int n_in,
                              void* d_out, int out_size, void* d_ws, size_t ws_size,
                              hipStream_t stream) {
  const float* X = (const float*)d_in[0];
  const float* W = (const float*)d_in[1];
  float* Out = (float*)d_out;
  dim3 grid(NOUT / TILE, NROW / TILE, NEXP);  // (32, 32, 8)
  moe_gemm_bf16<<<grid, dim3(512, 1, 1), 0, stream>>>(X, W, Out);
}